// Round 12
// baseline (334.219 us; speedup 1.0000x reference)
//
// NeuralExecutor2 — r12: single persistent kernel + device-scope grid barriers.
// Theory: the 115 µs plateau is per-dispatch-boundary cost (launch+drain+L2
// writeback for cross-XCD visibility), ~20 µs each; in-kernel micro-opts were
// neutral 3 rounds running. This collapses 4 kernels -> init + 1 persistent
// kernel (1024 blocks = exactly 4/CU co-resident), 2 sense-reversing grid
// barriers, m3-phase reuses m2's staged adj/e LDS. Spin is capped (no hangs).
#include <hip/hip_runtime.h>

#define XN 512
#define XB 4
#define XNEG  (-3.402823466e38f)
#define XMASK (-1.0e38f)
#define NBLK 1024

__device__ __forceinline__ float xscrub(float v) {
    unsigned u = __float_as_uint(v);
    u = ((u & 0x7f800000u) == 0x7f800000u) ? 0xff7fffffu : u;  // inf/nan -> -FLT_MAX bits
    return __uint_as_float(u);
}

// init: zero barrier words + tau (ws/out are poisoned 0xAA before every launch)
__global__ __launch_bounds__(64) void ne2p_init(unsigned* __restrict__ bar,
                                                float* __restrict__ tau)
{
    if (threadIdx.x < 2) bar[threadIdx.x] = 0u;   // [0]=cnt [1]=gen
    if (threadIdx.x < XB) tau[threadIdx.x] = 0.f;
}

// sense-reversing grid barrier, device scope, reusable; capped spin (no hang)
__device__ __forceinline__ void gridbar(unsigned* __restrict__ cnt,
                                        unsigned* __restrict__ gen)
{
    __syncthreads();
    if (threadIdx.x == 0) {
        __threadfence();  // publish this block's stores (agent scope)
        const unsigned g = __hip_atomic_load(gen, __ATOMIC_RELAXED, __HIP_MEMORY_SCOPE_AGENT);
        const unsigned a = __hip_atomic_fetch_add(cnt, 1u, __ATOMIC_ACQ_REL, __HIP_MEMORY_SCOPE_AGENT) + 1u;
        if (a == (unsigned)NBLK) {
            __hip_atomic_store(cnt, 0u, __ATOMIC_RELAXED, __HIP_MEMORY_SCOPE_AGENT);
            __hip_atomic_fetch_add(gen, 1u, __ATOMIC_RELEASE, __HIP_MEMORY_SCOPE_AGENT);
        } else {
            long it = 0;
            while (__hip_atomic_load(gen, __ATOMIC_ACQUIRE, __HIP_MEMORY_SCOPE_AGENT) == g) {
                __builtin_amdgcn_s_sleep(2);
                if (++it > (1L << 27)) break;     // visible-fail safety valve
            }
        }
        __threadfence();
    }
    __syncthreads();
}

__global__ __launch_bounds__(256, 4) void ne2p_all(
    const float* __restrict__ x, const float* __restrict__ h,
    const int* __restrict__ adj, const float* __restrict__ ef,
    const float* __restrict__ Wn, const float* __restrict__ We,
    const float* __restrict__ Wm, const float* __restrict__ Wu,
    const float* __restrict__ Wtm, const float* __restrict__ Wtu,
    const float* __restrict__ Wd, const float* __restrict__ Wt,
    const float* __restrict__ Wp,
    float* __restrict__ B1g, float* __restrict__ B2g, float* __restrict__ hp2g,
    unsigned* __restrict__ bar,
    float* __restrict__ o_newx, float* __restrict__ o_p,
    float* __restrict__ o_tau, float* __restrict__ o_newh)
{
    const int q = blockIdx.x;                 // 0..1023
    const int b = q >> 8;                     // 256 blocks per batch
    const int i0 = (q & 255) * 2;
    const int row0 = b * XN + i0;
    const int t = threadIdx.x;

    __shared__ float emf[2 * XN];             // [j*2+r]: e or 0
    __shared__ float adf[2 * XN];             // [j*2+r]: 0 or -1e38
    __shared__ float wush[2048], wtmsh[2048];
    __shared__ float wdsh[192], wpsh[64];
    __shared__ float drvs[132];               // c1|c2|u1|u2|cp (per-block recompute)
    __shared__ float zs[64], a1s[64], ags[64], nhs[64], a2s[64], ssx[64];
    __shared__ float red[2][8][33];
    __shared__ float hp2s[XN];
    __shared__ float hp1s[2];

    // ================= phase 0: staging + encoder + per-block drv =============
    {
        const int*   ab = adj + (size_t)row0 * XN;
        const float* eb = ef  + (size_t)row0 * XN;
        for (int u = t; u < 2 * XN; u += 256) {
            const int r = u >> 9, j = u & (XN - 1);
            const int on = (ab[u] != 0) | (j == i0 + r);
            emf[j * 2 + r] = on ? eb[u] : 0.f;
            adf[j * 2 + r] = on ? 0.f : XMASK;
        }
        const float4* wu4 = (const float4*)Wu;
        const float4* wt4 = (const float4*)Wtm;
        ((float4*)wush)[t]        = wu4[t];
        ((float4*)wush)[t + 256]  = wu4[t + 256];
        ((float4*)wtmsh)[t]       = wt4[t];
        ((float4*)wtmsh)[t + 256] = wt4[t + 256];
        if (t < 192) wdsh[t] = Wd[t];
        if (t < 64)  wpsh[t] = Wp[t];
    }
    if (t < 64) {                             // z for this block's 2 rows
        const int r = t >> 5, l = t & 31;
        const int row = row0 + r;
        const float* xr = x + row * 3;
        const float* hr = h + row * 32;
        float acc = 0.f;
        for (int k = 0; k < 3; ++k)  acc += xr[k] * Wn[k * 32 + l];
        for (int k = 0; k < 32; ++k) acc += hr[k] * Wn[(3 + k) * 32 + l];
        zs[t] = acc;
    } else if (t < 96) {                      // c1,c2
        const int l = t - 64;
        float c1 = 0.f, c2 = 0.f;
        for (int k = 0; k < 32; ++k) {
            const float w = We[k];
            c1 += w * Wm[(64 + k) * 32 + l];
            c2 += w * Wtm[(64 + k) * 32 + l];
        }
        drvs[l] = c1; drvs[32 + l] = c2;
    } else if (t < 128) {                     // u1,u2
        const int l = t - 96;
        float u1 = 0.f, u2 = 0.f;
        for (int k = 0; k < 32; ++k) {
            u1 += Wtu[l * 32 + k]        * Wt[k];
            u2 += Wtu[(32 + l) * 32 + k] * Wt[k];
        }
        drvs[64 + l] = u1; drvs[96 + l] = u2;
    } else if (t == 128) {                    // cp
        float cp = 0.f;
        for (int k = 0; k < 32; ++k) cp += We[k] * Wp[64 + k];
        drvs[128] = cp;
    }
    __syncthreads();
    if (t < 64) {                             // A1 (LDS) + B1 (global, cross-block)
        const int r = t >> 5, l = t & 31;
        float a = 0.f, bb = 0.f;
        for (int k = 0; k < 32; ++k) {
            const float zk = zs[r * 32 + k];
            a  += zk * Wm[k * 32 + l];
            bb += zk * Wm[(32 + k) * 32 + l];
        }
        a1s[t] = a;
        B1g[row0 * 32 + t] = bb;
    }

    gridbar(bar, bar + 1);                    // ---- all B1 visible ----

    // ================= phase 1: mpnn1 scan + epilogue =========================
    const int c = t >> 5, l = t & 31;
    {
        const float c1v = drvs[l];
        const float* Bp = B1g + (size_t)b * XN * 32 + l;
        const int j0 = c * 64;
        float m0 = XNEG, m1 = XNEG;
#pragma unroll 8
        for (int k = 0; k < 64; ++k) {
            const int j = j0 + k;
            const float bv = Bp[(size_t)j * 32];
            m0 = fmaxf(m0, fmaf(emf[j * 2],     c1v, bv) + adf[j * 2]);
            m1 = fmaxf(m1, fmaf(emf[j * 2 + 1], c1v, bv) + adf[j * 2 + 1]);
        }
        red[0][c][l] = m0;
        red[1][c][l] = m1;
    }
    __syncthreads();
    if (t < 64) {
        const int r = t >> 5, ll = t & 31;
        float mm = red[r][0][ll];
        for (int cc = 1; cc < 8; ++cc) mm = fmaxf(mm, red[r][cc][ll]);
        ags[t] = a1s[t] + mm;
    }
    __syncthreads();
    if (t < 64) {                             // new_h
        const int r = t >> 5, ll = t & 31;
        float v = zs[t];
        for (int k = 0; k < 32; ++k)
            v += zs[r * 32 + k] * wush[k * 32 + ll]
               + ags[r * 32 + k] * wush[(32 + k) * 32 + ll];
        nhs[t] = v;
        o_newh[row0 * 32 + t] = v;
    }
    __syncthreads();
    if (t < 64) {                             // A2 (LDS) + B2 (global)
        const int r = t >> 5, ll = t & 31;
        float a2 = 0.f, b2 = 0.f;
        for (int k = 0; k < 32; ++k) {
            const float nk = nhs[r * 32 + k];
            a2 += nk * wtmsh[k * 32 + ll];
            b2 += nk * wtmsh[(32 + k) * 32 + ll];
        }
        a2s[t] = a2;
        B2g[row0 * 32 + t] = b2;
    } else if (t >= 128 && t < 132) {         // hp1 (LDS) / hp2 (global)
        const int r = (t - 128) >> 1, which = (t - 128) & 1;
        float p = 0.f;
        for (int k = 0; k < 32; ++k) p += nhs[r * 32 + k] * wpsh[which * 32 + k];
        if (which) hp2g[b * XN + i0 + r] = p; else hp1s[r] = p;
    } else if (t >= 160 && t < 166) {         // new_x
        const int idx = t - 160, r = idx / 3, d = idx % 3;
        float v = 0.f;
        for (int k = 0; k < 32; ++k)
            v += zs[r * 32 + k] * wdsh[k * 3 + d]
               + nhs[r * 32 + k] * wdsh[(32 + k) * 3 + d];
        o_newx[(row0 + r) * 3 + d] = v;
    }

    gridbar(bar, bar + 1);                    // ---- all B2, hp2 visible ----

    // ================= phase 2: p-head + termination scan + tau ===============
    for (int u = t; u < XN; u += 256) hp2s[u] = hp2g[b * XN + u];
    __syncthreads();
    {
        const float cpv = drvs[128];
        const float h1a = hp1s[0], h1b = hp1s[1];
        float* pr0 = o_p + (size_t)row0 * XN;
        float* pr1 = pr0 + XN;
        for (int j = t; j < XN; j += 256) {   // adj/e mask LDS reused — no restage
            pr0[j] = xscrub(h1a + hp2s[j] + emf[j * 2]     * cpv + adf[j * 2]);
            pr1[j] = xscrub(h1b + hp2s[j] + emf[j * 2 + 1] * cpv + adf[j * 2 + 1]);
        }
    }
    {
        const float c2v = drvs[32 + l];
        const float* Bp = B2g + (size_t)b * XN * 32 + l;
        const int j0 = c * 64;
        float m0 = XNEG, m1 = XNEG;
#pragma unroll 8
        for (int k = 0; k < 64; ++k) {
            const int j = j0 + k;
            const float bv = Bp[(size_t)j * 32];
            m0 = fmaxf(m0, fmaf(emf[j * 2],     c2v, bv) + adf[j * 2]);
            m1 = fmaxf(m1, fmaf(emf[j * 2 + 1], c2v, bv) + adf[j * 2 + 1]);
        }
        red[0][c][l] = m0;
        red[1][c][l] = m1;
    }
    __syncthreads();
    if (t < 64) {
        const int r = t >> 5, ll = t & 31;
        float mm = red[r][0][ll];
        for (int cc = 1; cc < 8; ++cc) mm = fmaxf(mm, red[r][cc][ll]);
        const float agg = a2s[t] + mm;
        ssx[t] = nhs[t] * drvs[64 + ll] + agg * drvs[96 + ll];
    }
    __syncthreads();
    if (t < 64) {
        float s = ssx[t];
        s += __shfl_down(s, 32);
        s += __shfl_down(s, 16);
        s += __shfl_down(s, 8);
        s += __shfl_down(s, 4);
        s += __shfl_down(s, 2);
        s += __shfl_down(s, 1);
        if (t == 0) atomicAdd(&o_tau[b], s * (1.0f / XN));
    }
}

extern "C" void kernel_launch(void* const* d_in, const int* in_sizes, int n_in,
                              void* d_out, int out_size, void* d_ws, size_t ws_size,
                              hipStream_t stream)
{
    const float* x   = (const float*)d_in[0];
    const float* h   = (const float*)d_in[1];
    const int*   adj = (const int*)  d_in[2];
    const float* ef  = (const float*)d_in[3];
    const float* Wn  = (const float*)d_in[4];
    const float* We  = (const float*)d_in[5];
    const float* Wm  = (const float*)d_in[6];
    const float* Wu  = (const float*)d_in[7];
    const float* Wtm = (const float*)d_in[8];
    const float* Wtu = (const float*)d_in[9];
    const float* Wd  = (const float*)d_in[10];
    const float* Wt  = (const float*)d_in[11];
    const float* Wp  = (const float*)d_in[12];

    float* out    = (float*)d_out;
    float* o_newx = out;                          // [4,512,3]   6144
    float* o_p    = out + 6144;                   // [4,512,512] 1048576
    float* o_tau  = out + 6144 + XB * XN * XN;    // [4,1]       4
    float* o_newh = o_tau + XB;                   // [4,512,32]  65536

    float* w = (float*)d_ws;
    const int RN = XB * XN * 32;                  // 65536
    float*    B1g  = w;
    float*    B2g  = w + RN;
    float*    hp2g = w + 2 * RN;
    unsigned* bar  = (unsigned*)(w + 2 * RN + XB * XN);

    hipLaunchKernelGGL(ne2p_init, dim3(1), dim3(64), 0, stream, bar, o_tau);
    hipLaunchKernelGGL(ne2p_all, dim3(NBLK), dim3(256), 0, stream,
                       x, h, adj, ef, Wn, We, Wm, Wu, Wtm, Wtu, Wd, Wt, Wp,
                       B1g, B2g, hp2g, bar, o_newx, o_p, o_tau, o_newh);
}

// Round 13
// 175.515 us; speedup vs baseline: 1.9042x; 1.9042x over previous
//
// NeuralExecutor2 — r13: 2 self-contained kernels, no cross-block deps inside
// a kernel. Each block recomputes batch z into LDS (TI=8 -> 1 block/CU, ~0.6M
// fma redundancy) and fuses B1/B2 dots into the scan registers — eliminates
// g0/g1 kernels and all global B-matrix round-trips. Mask sign-encoded
// (e in [0,1); masked = -1.0f). r12 taught: grid atomics barrier = 120us; the
// real compute is ~7us; harness floor (fill+restores+gaps) ~80us.
#include <hip/hip_runtime.h>

#define XN 512
#define XNEG  (-3.402823466e38f)
#define XSENT (-1.0e30f)

__device__ __forceinline__ float xscrub(float v) {
    unsigned u = __float_as_uint(v);
    u = ((u & 0x7f800000u) == 0x7f800000u) ? 0xff7fffffu : u;  // inf/nan -> -FLT_MAX bits
    return __uint_as_float(u);
}

// ---------------- K1: z-GEMM + mpnn1 scan + new_h/new_x ----------------
// 256 blocks (64/batch, 8 rows each). LDS ~91KB -> 1 block/CU.
__global__ __launch_bounds__(256, 2) void ne2q_k1(
    const float* __restrict__ x, const float* __restrict__ h,
    const int* __restrict__ adj, const float* __restrict__ ef,
    const float* __restrict__ Wn, const float* __restrict__ We,
    const float* __restrict__ Wm, const float* __restrict__ Wu,
    const float* __restrict__ Wd,
    float* __restrict__ o_newx, float* __restrict__ o_newh,
    float* __restrict__ o_tau)
{
    const int q = blockIdx.x;                 // 0..255
    const int b = q >> 6;                     // 64 blocks per batch
    const int i0 = (q & 63) * 8;
    const int row0 = b * XN + i0;
    const int t = threadIdx.x;

    __shared__ float zL[XN * 32];             // 64 KB: z for the whole batch
    __shared__ float em[8 * XN];              // 16 KB: [r][j] = e (>=0) or -1 (masked)
    __shared__ float red[8][8][33];           // scan partials
    __shared__ float agL[8 * 32], nhL[8 * 32];

    if (q == 0 && t < 4) o_tau[t] = 0.f;      // K2 accumulates into tau

    // stage mask/e for own 8 rows (coalesced; em layout [r*512+j])
    {
        const int*   ab = adj + (size_t)row0 * XN;
        const float* eb = ef  + (size_t)row0 * XN;
        for (int u = t; u < 8 * XN; u += 256) {
            const int r = u >> 9, j = u & (XN - 1);
            const int on = (ab[u] != 0) | (j == i0 + r);
            em[u] = on ? eb[u] : -1.0f;       // e in [0,1) => sign bit = mask
        }
    }

    // z-GEMM: thread (c,l) computes z[j,l] for j in its 64-row span
    const int c = t >> 5, l = t & 31;
    {
        float wn[35];
#pragma unroll
        for (int k = 0; k < 35; ++k) wn[k] = Wn[k * 32 + l];
        const float* xb = x + (size_t)(b * XN) * 3;
        const float* hb = h + (size_t)(b * XN) * 32;
        const int j1 = c * 64 + 64;
        for (int j = c * 64; j < j1; ++j) {
            const float* hr = hb + j * 32;
            float acc = xb[j * 3] * wn[0] + xb[j * 3 + 1] * wn[1] + xb[j * 3 + 2] * wn[2];
#pragma unroll
            for (int k = 0; k < 32; ++k) acc += hr[k] * wn[3 + k];
            zL[j * 32 + l] = acc;
        }
    }
    __syncthreads();

    // scan: B1[j,l] computed in-register (dot over zL), masked max over j
    {
        float wm2[32];
#pragma unroll
        for (int k = 0; k < 32; ++k) wm2[k] = Wm[(32 + k) * 32 + l];
        float c1v = 0.f;
#pragma unroll
        for (int k = 0; k < 32; ++k) c1v += We[k] * Wm[(64 + k) * 32 + l];

        float m[8];
#pragma unroll
        for (int r = 0; r < 8; ++r) m[r] = XNEG;
        const int j1 = c * 64 + 64;
        for (int j = c * 64; j < j1; ++j) {
            float bv = 0.f;
#pragma unroll
            for (int k = 0; k < 32; ++k) bv += zL[j * 32 + k] * wm2[k];
#pragma unroll
            for (int r = 0; r < 8; ++r) {
                const float s = em[r * XN + j];
                const float v = fmaf(s, c1v, bv);
                m[r] = (s >= 0.f) ? fmaxf(m[r], v) : m[r];
            }
        }
#pragma unroll
        for (int r = 0; r < 8; ++r) red[r][c][l] = m[r];
    }
    __syncthreads();

    // agg = A1(own) + max over c
    {
        const int r = t >> 5, ll = t & 31;
        float mm = red[r][0][ll];
#pragma unroll
        for (int cc = 1; cc < 8; ++cc) mm = fmaxf(mm, red[r][cc][ll]);
        float a1 = 0.f;
        const float* zr = zL + (i0 + r) * 32;
#pragma unroll
        for (int k = 0; k < 32; ++k) a1 += zr[k] * Wm[k * 32 + ll];
        agL[t] = a1 + mm;
    }
    __syncthreads();

    // new_h (residual + update linear)
    {
        const int r = t >> 5, ll = t & 31;
        const float* zr = zL + (i0 + r) * 32;
        float v = zr[ll];
#pragma unroll
        for (int k = 0; k < 32; ++k)
            v += zr[k] * Wu[k * 32 + ll] + agL[r * 32 + k] * Wu[(32 + k) * 32 + ll];
        nhL[t] = v;
        o_newh[(size_t)row0 * 32 + t] = v;
    }
    __syncthreads();

    // new_x (8 rows x 3)
    if (t < 24) {
        const int r = t / 3, d = t % 3;
        const float* zr = zL + (i0 + r) * 32;
        float v = 0.f;
#pragma unroll
        for (int k = 0; k < 32; ++k)
            v += zr[k] * Wd[k * 3 + d] + nhL[r * 32 + k] * Wd[(32 + k) * 3 + d];
        o_newx[(row0 + r) * 3 + d] = v;
    }
}

// ---------------- K2: termination scan + p-head + tau ----------------
__global__ __launch_bounds__(256, 2) void ne2q_k2(
    const int* __restrict__ adj, const float* __restrict__ ef,
    const float* __restrict__ newh, const float* __restrict__ We,
    const float* __restrict__ Wtm, const float* __restrict__ Wtu,
    const float* __restrict__ Wt, const float* __restrict__ Wp,
    float* __restrict__ o_p, float* __restrict__ o_tau)
{
    const int q = blockIdx.x;
    const int b = q >> 6;
    const int i0 = (q & 63) * 8;
    const int row0 = b * XN + i0;
    const int t = threadIdx.x;

    __shared__ float nhL[XN * 32];            // 64 KB: new_h for the batch
    __shared__ float em[8 * XN];              // 16 KB
    __shared__ float red[8][8][33];
    __shared__ float hp2L[XN];
    __shared__ float hp1L[8];
    __shared__ float part[4];

    // stage: new_h batch (float4 coalesced) + mask/e own rows
    {
        const float4* src = (const float4*)(newh + (size_t)b * XN * 32);
        float4* dst = (float4*)nhL;
        for (int u = t; u < XN * 8; u += 256) dst[u] = src[u];
        const int*   ab = adj + (size_t)row0 * XN;
        const float* eb = ef  + (size_t)row0 * XN;
        for (int u = t; u < 8 * XN; u += 256) {
            const int r = u >> 9, j = u & (XN - 1);
            const int on = (ab[u] != 0) | (j == i0 + r);
            em[u] = on ? eb[u] : -1.0f;
        }
    }
    __syncthreads();

    const int c = t >> 5, l = t & 31;
    // scan with in-register B2 dots + hp2 (all j) + hp1 (own rows)
    {
        float wt2[32];
#pragma unroll
        for (int k = 0; k < 32; ++k) wt2[k] = Wtm[(32 + k) * 32 + l];
        float c2v = 0.f;
#pragma unroll
        for (int k = 0; k < 32; ++k) c2v += We[k] * Wtm[(64 + k) * 32 + l];

        float m[8];
#pragma unroll
        for (int r = 0; r < 8; ++r) m[r] = XNEG;
        const int j1 = c * 64 + 64;
        for (int j = c * 64; j < j1; ++j) {
            float bv = 0.f;
#pragma unroll
            for (int k = 0; k < 32; ++k) bv += nhL[j * 32 + k] * wt2[k];
#pragma unroll
            for (int r = 0; r < 8; ++r) {
                const float s = em[r * XN + j];
                const float v = fmaf(s, c2v, bv);
                m[r] = (s >= 0.f) ? fmaxf(m[r], v) : m[r];
            }
        }
#pragma unroll
        for (int r = 0; r < 8; ++r) red[r][c][l] = m[r];

        for (int j2 = t; j2 < XN; j2 += 256) {     // hp2[j] = nh[j]·Wp[32:64]
            float p = 0.f;
#pragma unroll
            for (int k = 0; k < 32; ++k) p += nhL[j2 * 32 + k] * Wp[32 + k];
            hp2L[j2] = p;
        }
        if (t < 8) {                                // hp1 own rows
            float p = 0.f;
#pragma unroll
            for (int k = 0; k < 32; ++k) p += nhL[(i0 + t) * 32 + k] * Wp[k];
            hp1L[t] = p;
        }
    }
    __syncthreads();

    // p-head: 8 rows x 512 cols (sole writer; bit-scrubbed -> provably finite)
    {
        float cpv = 0.f;
#pragma unroll
        for (int k = 0; k < 32; ++k) cpv += We[k] * Wp[64 + k];
#pragma unroll
        for (int r = 0; r < 8; ++r) {
            float* pr = o_p + (size_t)(row0 + r) * XN;
            const float h1 = hp1L[r];
            for (int j = t; j < XN; j += 256) {
                const float s = em[r * XN + j];
                const float v = (s >= 0.f) ? (h1 + hp2L[j] + s * cpv) : XSENT;
                pr[j] = xscrub(v);
            }
        }
    }

    // tau: ss[r,l] = nh·u1[l] + (A2+mm)·u2[l]; block-reduce; atomic per batch
    float ss;
    {
        const int r = t >> 5, ll = t & 31;
        float mm = red[r][0][ll];
#pragma unroll
        for (int cc = 1; cc < 8; ++cc) mm = fmaxf(mm, red[r][cc][ll]);
        const float* nr = nhL + (i0 + r) * 32;
        float a2 = 0.f;
#pragma unroll
        for (int k = 0; k < 32; ++k) a2 += nr[k] * Wtm[k * 32 + ll];
        float u1 = 0.f, u2 = 0.f;
#pragma unroll
        for (int k = 0; k < 32; ++k) {
            u1 += Wtu[ll * 32 + k]        * Wt[k];
            u2 += Wtu[(32 + ll) * 32 + k] * Wt[k];
        }
        ss = nr[ll] * u1 + (a2 + mm) * u2;
    }
    // wave reduce (64 lanes) then cross-wave
    ss += __shfl_down(ss, 32);
    ss += __shfl_down(ss, 16);
    ss += __shfl_down(ss, 8);
    ss += __shfl_down(ss, 4);
    ss += __shfl_down(ss, 2);
    ss += __shfl_down(ss, 1);
    if ((t & 63) == 0) part[t >> 6] = ss;
    __syncthreads();
    if (t == 0) {
        const float s = part[0] + part[1] + part[2] + part[3];
        atomicAdd(&o_tau[b], s * (1.0f / XN));
    }
}

extern "C" void kernel_launch(void* const* d_in, const int* in_sizes, int n_in,
                              void* d_out, int out_size, void* d_ws, size_t ws_size,
                              hipStream_t stream)
{
    const float* x   = (const float*)d_in[0];
    const float* h   = (const float*)d_in[1];
    const int*   adj = (const int*)  d_in[2];
    const float* ef  = (const float*)d_in[3];
    const float* Wn  = (const float*)d_in[4];
    const float* We  = (const float*)d_in[5];
    const float* Wm  = (const float*)d_in[6];
    const float* Wu  = (const float*)d_in[7];
    const float* Wtm = (const float*)d_in[8];
    const float* Wtu = (const float*)d_in[9];
    const float* Wd  = (const float*)d_in[10];
    const float* Wt  = (const float*)d_in[11];
    const float* Wp  = (const float*)d_in[12];

    float* out    = (float*)d_out;
    float* o_newx = out;                          // [4,512,3]   6144
    float* o_p    = out + 6144;                   // [4,512,512] 1048576
    float* o_tau  = out + 6144 + 4 * XN * XN;     // [4,1]       4
    float* o_newh = o_tau + 4;                    // [4,512,32]  65536

    hipLaunchKernelGGL(ne2q_k1, dim3(256), dim3(256), 0, stream,
                       x, h, adj, ef, Wn, We, Wm, Wu, Wd,
                       o_newx, o_newh, o_tau);
    hipLaunchKernelGGL(ne2q_k2, dim3(256), dim3(256), 0, stream,
                       adj, ef, o_newh, We, Wtm, Wtu, Wt, Wp,
                       o_p, o_tau);
}